// Round 1
// baseline (139.970 us; speedup 1.0000x reference)
//
#include <hip/hip_runtime.h>
#include <math.h>

#define NN    20000
#define KOFF  8
#define NK    (NN*KOFF)       // 160000
#define NEDGE (2*NK)          // 320000
#define HID   256
#define INFEAT 128

__device__ __forceinline__ float sigmoidf_(float x) { return 1.0f / (1.0f + expf(-x)); }

// ---------------- Tiled f32 GEMM: C[M,N] = X[M,Kd] @ W[Kd,N] ----------------
// TILE 64x64, BK=16, 256 threads, 4x4 micro-tile per thread.
#define TM 64
#define TN 64
#define TK 16
#define LDP 68   // padded leading dim (keeps 16B alignment, breaks bank aliasing)

__global__ __launch_bounds__(256) void gemm_f32(const float* __restrict__ X,
                                                const float* __restrict__ W,
                                                float* __restrict__ C,
                                                int M, int Kd, int N)
{
    __shared__ float Xs[TK][LDP];   // transposed X tile: Xs[k][row]
    __shared__ float Ws[TK][LDP];   // Ws[k][col]

    const int bm = blockIdx.x * TM;
    const int bn = blockIdx.y * TN;
    const int t  = threadIdx.x;
    const int tx = t & 15;          // 0..15 -> col group
    const int ty = t >> 4;          // 0..15 -> row group

    float acc[4][4] = {};

    for (int k0 = 0; k0 < Kd; k0 += TK) {
        // Load X tile: 64 rows x 16 k.  thread -> row=t>>2, kcol=(t&3)*4 (float4)
        {
            const int r   = t >> 2;
            const int c   = (t & 3) << 2;
            const int row = bm + r;
            float4 v = make_float4(0.f, 0.f, 0.f, 0.f);
            if (row < M)
                v = *reinterpret_cast<const float4*>(X + (size_t)row * Kd + k0 + c);
            Xs[c + 0][r] = v.x;
            Xs[c + 1][r] = v.y;
            Xs[c + 2][r] = v.z;
            Xs[c + 3][r] = v.w;
        }
        // Load W tile: 16 k x 64 cols. thread -> k=t>>4, col=(t&15)*4 (float4)
        {
            const int r = t >> 4;
            const int c = (t & 15) << 2;
            const float4 v = *reinterpret_cast<const float4*>(W + (size_t)(k0 + r) * N + bn + c);
            *reinterpret_cast<float4*>(&Ws[r][c]) = v;
        }
        __syncthreads();

        #pragma unroll
        for (int k = 0; k < TK; ++k) {
            const float4 a = *reinterpret_cast<const float4*>(&Xs[k][ty << 2]);
            const float4 b = *reinterpret_cast<const float4*>(&Ws[k][tx << 2]);
            const float av[4] = {a.x, a.y, a.z, a.w};
            const float bv[4] = {b.x, b.y, b.z, b.w};
            #pragma unroll
            for (int i = 0; i < 4; ++i)
                #pragma unroll
                for (int j = 0; j < 4; ++j)
                    acc[i][j] += av[i] * bv[j];
        }
        __syncthreads();
    }

    #pragma unroll
    for (int i = 0; i < 4; ++i) {
        const int row = bm + (ty << 2) + i;
        if (row < M) {
            float4 v = make_float4(acc[i][0], acc[i][1], acc[i][2], acc[i][3]);
            *reinterpret_cast<float4*>(C + (size_t)row * N + bn + (tx << 2)) = v;
        }
    }
}

// ---------------- 17-tap circular aggregation (+bias, optional relu) ----------------
template<bool RELU>
__global__ __launch_bounds__(256) void agg_kernel(const float* __restrict__ H,
                                                  const float* __restrict__ bias,
                                                  float* __restrict__ out)
{
    const int idx = blockIdx.x * 256 + threadIdx.x;   // one float4 per thread
    if (idx >= NN * (HID / 4)) return;
    const int v = idx >> 6;          // node
    const int f = (idx & 63) << 2;   // feature start

    float sx = 0.f, sy = 0.f, sz = 0.f, sw = 0.f;
    #pragma unroll
    for (int o = -8; o <= 8; ++o) {
        int vv = v + o;
        vv = (vv < 0) ? vv + NN : ((vv >= NN) ? vv - NN : vv);
        const float4 tt = *reinterpret_cast<const float4*>(H + (size_t)vv * HID + f);
        sx += tt.x; sy += tt.y; sz += tt.z; sw += tt.w;
    }
    const float inv17 = 1.0f / 17.0f;
    const float4 bb = *reinterpret_cast<const float4*>(bias + f);
    float4 r;
    r.x = sx * inv17 + bb.x;
    r.y = sy * inv17 + bb.y;
    r.z = sz * inv17 + bb.z;
    r.w = sw * inv17 + bb.w;
    if (RELU) {
        r.x = fmaxf(r.x, 0.f); r.y = fmaxf(r.y, 0.f);
        r.z = fmaxf(r.z, 0.f); r.w = fmaxf(r.w, 0.f);
    }
    *reinterpret_cast<float4*>(out + (size_t)v * HID + f) = r;
}

// ---------------- BatchNorm stats (two-stage, deterministic) ----------------
#define BN_BLOCKS 80
#define BN_ROWS   (NN / BN_BLOCKS)   // 250

__global__ __launch_bounds__(256) void bn_partial(const float* __restrict__ A,
                                                  float* __restrict__ partial)
{
    const int b = blockIdx.x;
    const int t = threadIdx.x;       // feature column
    const int r0 = b * BN_ROWS;
    float s = 0.f, s2 = 0.f;
    for (int r = r0; r < r0 + BN_ROWS; ++r) {
        const float x = A[(size_t)r * HID + t];
        s += x; s2 += x * x;
    }
    partial[(size_t)b * 2 * HID + t]       = s;
    partial[(size_t)b * 2 * HID + HID + t] = s2;
}

__global__ __launch_bounds__(256) void bn_finalize(const float* __restrict__ partial,
                                                   const float* __restrict__ gamma,
                                                   const float* __restrict__ beta,
                                                   float* __restrict__ ss)
{
    const int t = threadIdx.x;
    float s = 0.f, s2 = 0.f;
    for (int b = 0; b < BN_BLOCKS; ++b) {
        s  += partial[(size_t)b * 2 * HID + t];
        s2 += partial[(size_t)b * 2 * HID + HID + t];
    }
    const float invn = 1.0f / (float)NN;
    const float mu   = s * invn;
    const float var  = s2 * invn - mu * mu;
    const float sc   = gamma[t] * rsqrtf(var + 1e-5f);
    ss[t]        = sc;
    ss[HID + t]  = beta[t] - mu * sc;
}

__global__ __launch_bounds__(256) void bn_relu(float* __restrict__ A,
                                               const float* __restrict__ ss)
{
    const int idx = blockIdx.x * 256 + threadIdx.x;
    if (idx >= NN * (HID / 4)) return;
    const int f = (idx & 63) << 2;
    float4 v = *reinterpret_cast<float4*>(A + (size_t)idx * 4);
    const float4 sc = *reinterpret_cast<const float4*>(ss + f);
    const float4 sh = *reinterpret_cast<const float4*>(ss + HID + f);
    v.x = fmaxf(v.x * sc.x + sh.x, 0.f);
    v.y = fmaxf(v.y * sc.y + sh.y, 0.f);
    v.z = fmaxf(v.z * sc.z + sh.z, 0.f);
    v.w = fmaxf(v.w * sc.w + sh.w, 0.f);
    *reinterpret_cast<float4*>(A + (size_t)idx * 4) = v;
}

// ---------------- per-node dots u = h2.Wl[:256], w = h2.Wl[256:] ----------------
__global__ __launch_bounds__(256) void dots_kernel(const float* __restrict__ h2,
                                                   const float* __restrict__ Wl,
                                                   float* __restrict__ u,
                                                   float* __restrict__ w)
{
    const int gid  = blockIdx.x * 256 + threadIdx.x;
    const int node = gid >> 6;
    const int lane = threadIdx.x & 63;
    if (node >= NN) return;
    const float4 hv = *reinterpret_cast<const float4*>(h2 + (size_t)node * HID + lane * 4);
    const float4 wa = *reinterpret_cast<const float4*>(Wl + lane * 4);
    const float4 wb = *reinterpret_cast<const float4*>(Wl + HID + lane * 4);
    float pu = hv.x * wa.x + hv.y * wa.y + hv.z * wa.z + hv.w * wa.w;
    float pw = hv.x * wb.x + hv.y * wb.y + hv.z * wb.z + hv.w * wb.w;
    #pragma unroll
    for (int off = 32; off > 0; off >>= 1) {
        pu += __shfl_down(pu, off);
        pw += __shfl_down(pw, off);
    }
    if (lane == 0) { u[node] = pu; w[node] = pw; }
}

// ---------------- P[v] = u[v] + 16*w[v] + sum_{o=1..8}(u[v+o]+u[v-o]) ----------------
__global__ __launch_bounds__(256) void compP(const float* __restrict__ u,
                                             const float* __restrict__ w,
                                             float* __restrict__ P)
{
    const int v = blockIdx.x * 256 + threadIdx.x;
    if (v >= NN) return;
    float s = u[v] + 16.0f * w[v];
    #pragma unroll
    for (int o = 1; o <= 8; ++o) {
        int vp = v + o;  if (vp >= NN) vp -= NN;
        int vm = v - o;  if (vm < 0)   vm += NN;
        s += u[vp] + u[vm];
    }
    P[v] = s;
}

// ---------------- final per-edge output ----------------
__global__ __launch_bounds__(256) void out_kernel(const float* __restrict__ P,
                                                  const float* __restrict__ w,
                                                  const float* __restrict__ blp,
                                                  float* __restrict__ out)
{
    const int c = blockIdx.x * 256 + threadIdx.x;
    if (c >= NEDGE) return;
    int v, t;
    if (c < NK) {
        v = c >> 3;
        t = v + 1 + (c & 7);
        if (t >= NN) t -= NN;
    } else {
        const int e = c - NK;
        t = e >> 3;
        v = t + 1 + (e & 7);
        if (v >= NN) v -= NN;
    }
    const float val = (P[v] + w[t]) * (1.0f / 17.0f) + blp[0];
    out[c] = sigmoidf_(val);
}

// ---------------- launch ----------------
extern "C" void kernel_launch(void* const* d_in, const int* in_sizes, int n_in,
                              void* d_out, int out_size, void* d_ws, size_t ws_size,
                              hipStream_t stream)
{
    const float* x      = (const float*)d_in[0];
    const float* W1     = (const float*)d_in[1];
    const float* b1     = (const float*)d_in[2];
    const float* gamma1 = (const float*)d_in[3];
    const float* beta1  = (const float*)d_in[4];
    const float* W2     = (const float*)d_in[5];
    const float* b2     = (const float*)d_in[6];
    const float* Wl     = (const float*)d_in[7];
    const float* bl     = (const float*)d_in[8];
    float* out = (float*)d_out;

    float* A       = (float*)d_ws;                 // [NN, HID]  agg1 -> h1 -> h2
    float* Bb      = A  + (size_t)NN * HID;        // [NN, HID]  H1 / H2 (pre-agg)
    float* partial = Bb + (size_t)NN * HID;        // [BN_BLOCKS, 2*HID]
    float* ss      = partial + (size_t)BN_BLOCKS * 2 * HID;  // [2*HID]
    float* u       = ss + 2 * HID;                 // [NN]
    float* wv      = u  + NN;                      // [NN]
    float* P       = wv + NN;                      // [NN]

    const int nAgg = (NN * (HID / 4) + 255) / 256; // 5000 blocks

    // 1) H1 = x @ W1
    dim3 g1((NN + TM - 1) / TM, HID / TN);
    gemm_f32<<<g1, 256, 0, stream>>>(x, W1, Bb, NN, INFEAT, HID);
    // 2) agg1 + b1
    agg_kernel<false><<<nAgg, 256, 0, stream>>>(Bb, b1, A);
    // 3) batch-norm stats + apply (+relu)
    bn_partial<<<BN_BLOCKS, 256, 0, stream>>>(A, partial);
    bn_finalize<<<1, 256, 0, stream>>>(partial, gamma1, beta1, ss);
    bn_relu<<<nAgg, 256, 0, stream>>>(A, ss);
    // 4) H2 = h1 @ W2
    gemm_f32<<<g1, 256, 0, stream>>>(A, W2, Bb, NN, HID, HID);
    // 5) agg2 + b2 + relu
    agg_kernel<true><<<nAgg, 256, 0, stream>>>(Bb, b2, A);
    // 6) u, w dots
    dots_kernel<<<(NN * 64 + 255) / 256, 256, 0, stream>>>(A, Wl, u, wv);
    // 7) P[v]
    compP<<<(NN + 255) / 256, 256, 0, stream>>>(u, wv, P);
    // 8) edge outputs
    out_kernel<<<(NEDGE + 255) / 256, 256, 0, stream>>>(P, wv, bl, out);
}

// Round 2
// 116.569 us; speedup vs baseline: 1.2007x; 1.2007x over previous
//
#include <hip/hip_runtime.h>
#include <hip/hip_bf16.h>
#include <math.h>

#define NN    20000
#define NK    160000          // NN*8
#define NEDGE 320000
#define HID   256
#define INFEAT 128
#define EPSF  1e-5f

typedef __bf16 bf16x8 __attribute__((ext_vector_type(8)));
typedef float  f32x4  __attribute__((ext_vector_type(4)));

__device__ __forceinline__ float sigmoidf_(float x) { return 1.0f / (1.0f + expf(-x)); }

__device__ __forceinline__ ushort f2bf(float f) {
    __hip_bfloat16 h = __float2bfloat16(f);
    return __builtin_bit_cast(ushort, h);
}

__device__ __forceinline__ int wrapN(int v) {
    return (v < 0) ? v + NN : ((v >= NN) ? v - NN : v);
}

#define LDSP(p) ((__attribute__((address_space(3))) unsigned int*)(p))
#define GBLP(p) ((const __attribute__((address_space(1))) unsigned int*)(p))
#define GLD16(g, l) __builtin_amdgcn_global_load_lds(GBLP(g), LDSP(l), 16, 0, 0)

// ---------------- prep: cast x -> bf16; build W1^T, W2^T in bf16 ----------------
// blocks [0,2500): xb (4 el/thread). [2500,2532): W1t. [2532,2596): W2t.
__global__ __launch_bounds__(256) void prep_kernel(const float* __restrict__ x,
                                                   const float* __restrict__ W1,
                                                   const float* __restrict__ W2,
                                                   ushort* __restrict__ xb,
                                                   ushort* __restrict__ W1t,
                                                   ushort* __restrict__ W2t)
{
    const int b = blockIdx.x, t = threadIdx.x;
    if (b < 2500) {
        const int idx = b * 1024 + t * 4;     // element index into x (2,560,000 total)
        const float4 v = *reinterpret_cast<const float4*>(x + idx);
        ushort4 o; o.x = f2bf(v.x); o.y = f2bf(v.y); o.z = f2bf(v.z); o.w = f2bf(v.w);
        *reinterpret_cast<ushort4*>(xb + idx) = o;
    } else if (b < 2532) {
        const int e = (b - 2500) * 1024 + t * 4;   // 32768 elements
        ushort4 o;
        #pragma unroll
        for (int j = 0; j < 4; ++j) {
            const int ee = e + j;
            const int n = ee >> 7, k = ee & 127;   // W1t[n][k] = W1[k][n]
            ((ushort*)&o)[j] = f2bf(W1[k * 256 + n]);
        }
        *reinterpret_cast<ushort4*>(W1t + e) = o;
    } else {
        const int e = (b - 2532) * 1024 + t * 4;   // 65536 elements
        ushort4 o;
        #pragma unroll
        for (int j = 0; j < 4; ++j) {
            const int ee = e + j;
            const int n = ee >> 8, k = ee & 255;   // W2t[n][k] = W2[k][n]
            ((ushort*)&o)[j] = f2bf(W2[k * 256 + n]);
        }
        *reinterpret_cast<ushort4*>(W2t + e) = o;
    }
}

// ---------------- MFMA bf16 GEMM: C[M,256] = A[M,K] @ B, B given as Bt[256][K] ----
// 64x64 tile, BK=64, 256 threads = 4 waves, wave -> 32x32 quadrant.
// LDS tiles [64 rows][64 k] bf16, row stride 128B, XOR-swizzled (byte ^= (row&7)<<4).
template<int K>
__global__ __launch_bounds__(256) void gemm_bf16(const ushort* __restrict__ Ab,
                                                 const ushort* __restrict__ Bt,
                                                 float* __restrict__ C)
{
    __shared__ alignas(16) char As[8192];
    __shared__ alignas(16) char Bs[8192];

    const int bm = blockIdx.x * 64;
    const int bn = blockIdx.y * 64;
    const int t = threadIdx.x;
    const int wave = t >> 6, lane = t & 63;
    const int wr = (wave >> 1) * 32;   // row quadrant
    const int wc = (wave & 1) * 32;    // col quadrant

    f32x4 acc[2][2] = {};

    for (int kt = 0; kt < K / 64; ++kt) {
        const int k0 = kt * 64;
        // stage A and B: per wave, 2 calls each of 1KB (64 lanes x 16B), linear dest.
        #pragma unroll
        for (int j = 0; j < 2; ++j) {
            const int c   = (wave + 4 * j) * 64 + lane;  // 16B-chunk index 0..511
            const int row = c >> 3;
            const int pk  = (c & 7) << 4;                // physical kbyte in row
            const int lk  = pk ^ ((row & 7) << 4);       // logical kbyte (inverse swizzle)
            int rg = bm + row; if (rg >= NN) rg = NN - 1;
            GLD16(Ab + (size_t)rg * K + k0 + (lk >> 1), As + (wave + 4 * j) * 1024);
            GLD16(Bt + (size_t)(bn + row) * K + k0 + (lk >> 1), Bs + (wave + 4 * j) * 1024);
        }
        __syncthreads();

        #pragma unroll
        for (int kk = 0; kk < 2; ++kk) {
            const int klog = kk * 64 + ((lane >> 4) << 4);   // logical byte offset in row
            bf16x8 af[2], bfv[2];
            #pragma unroll
            for (int mi = 0; mi < 2; ++mi) {
                const int row = wr + mi * 16 + (lane & 15);
                af[mi] = *reinterpret_cast<const bf16x8*>(As + row * 128 + (klog ^ ((row & 7) << 4)));
            }
            #pragma unroll
            for (int ni = 0; ni < 2; ++ni) {
                const int row = wc + ni * 16 + (lane & 15);
                bfv[ni] = *reinterpret_cast<const bf16x8*>(Bs + row * 128 + (klog ^ ((row & 7) << 4)));
            }
            #pragma unroll
            for (int mi = 0; mi < 2; ++mi)
                #pragma unroll
                for (int ni = 0; ni < 2; ++ni)
                    acc[mi][ni] = __builtin_amdgcn_mfma_f32_16x16x32_bf16(af[mi], bfv[ni], acc[mi][ni], 0, 0, 0);
        }
        __syncthreads();
    }

    // C/D layout: col = lane&15, row = (lane>>4)*4 + reg  (m89-verified)
    #pragma unroll
    for (int mi = 0; mi < 2; ++mi)
        #pragma unroll
        for (int ni = 0; ni < 2; ++ni)
            #pragma unroll
            for (int r = 0; r < 4; ++r) {
                const int row = bm + wr + mi * 16 + ((lane >> 4) << 2) + r;
                if (row < NN)
                    C[(size_t)row * 256 + bn + wc + ni * 16 + (lane & 15)] = acc[mi][ni][r];
            }
}

// ---------------- agg1 (rolling 17-tap) + bias, fused BN partial stats ----------
// 625 blocks x 32 nodes, 256 threads = feature columns.
__global__ __launch_bounds__(256) void agg1_bn(const float* __restrict__ H1,
                                               const float* __restrict__ b1,
                                               float* __restrict__ A,
                                               float* __restrict__ part)
{
    const int b = blockIdx.x, f = threadIdx.x;
    const int v0 = b * 32;
    const float bias = b1[f];
    float S = 0.f;
    #pragma unroll
    for (int o = -8; o <= 8; ++o)
        S += H1[(size_t)wrapN(v0 + o) * 256 + f];
    float s = 0.f, s2 = 0.f;
    const float inv17 = 1.0f / 17.0f;
    for (int i = 0; i < 32; ++i) {
        const int v = v0 + i;
        const float add = H1[(size_t)wrapN(v + 9) * 256 + f];
        const float sub = H1[(size_t)wrapN(v - 8) * 256 + f];
        const float val = S * inv17 + bias;
        A[(size_t)v * 256 + f] = val;
        s += val; s2 += val * val;
        S += add - sub;
    }
    part[(size_t)b * 512 + f]       = s;
    part[(size_t)b * 512 + 256 + f] = s2;
}

__global__ __launch_bounds__(512) void bn_finalize(const float* __restrict__ part,
                                                   const float* __restrict__ gamma,
                                                   const float* __restrict__ beta,
                                                   float* __restrict__ ss)
{
    const int t = threadIdx.x;
    __shared__ float red[512];
    float s = 0.f;
    #pragma unroll 8
    for (int b = 0; b < 625; ++b)
        s += part[(size_t)b * 512 + t];
    red[t] = s;
    __syncthreads();
    if (t < 256) {
        const float invn = 1.0f / (float)NN;
        const float mu   = red[t] * invn;
        const float var  = red[t + 256] * invn - mu * mu;
        const float sc   = gamma[t] * rsqrtf(var + EPSF);
        ss[t]       = sc;
        ss[256 + t] = beta[t] - mu * sc;
    }
}

// ---------------- BN apply + relu + cast to bf16 (feeds GEMM2) ----------------
__global__ __launch_bounds__(256) void bn_relu_cast(const float* __restrict__ A,
                                                    const float* __restrict__ ss,
                                                    ushort* __restrict__ h1b)
{
    const int idx = blockIdx.x * 256 + threadIdx.x;   // float4 index
    const int f = (idx & 63) << 2;
    float4 v = *reinterpret_cast<const float4*>(A + (size_t)idx * 4);
    const float4 sc = *reinterpret_cast<const float4*>(ss + f);
    const float4 sh = *reinterpret_cast<const float4*>(ss + 256 + f);
    ushort4 o;
    o.x = f2bf(fmaxf(v.x * sc.x + sh.x, 0.f));
    o.y = f2bf(fmaxf(v.y * sc.y + sh.y, 0.f));
    o.z = f2bf(fmaxf(v.z * sc.z + sh.z, 0.f));
    o.w = f2bf(fmaxf(v.w * sc.w + sh.w, 0.f));
    *reinterpret_cast<ushort4*>(h1b + (size_t)idx * 4) = o;
}

// ---------------- agg2 (rolling) + bias + relu + dot with Wl -> u, w ----------
__global__ __launch_bounds__(256) void agg2_dots(const float* __restrict__ H2,
                                                 const float* __restrict__ b2,
                                                 const float* __restrict__ Wl,
                                                 float* __restrict__ u,
                                                 float* __restrict__ w)
{
    const int b = blockIdx.x, t = threadIdx.x;
    const int wave = t >> 6, lane = t & 63;
    const int v0 = b * 32;
    const float wla = Wl[t], wlb = Wl[256 + t], bias = b2[t];
    __shared__ float Up[4][32], Wp[4][32];

    float S = 0.f;
    #pragma unroll
    for (int o = -8; o <= 8; ++o)
        S += H2[(size_t)wrapN(v0 + o) * 256 + t];

    const float inv17 = 1.0f / 17.0f;
    for (int i = 0; i < 32; ++i) {
        const int v = v0 + i;
        const float add = H2[(size_t)wrapN(v + 9) * 256 + t];
        const float sub = H2[(size_t)wrapN(v - 8) * 256 + t];
        const float h = fmaxf(S * inv17 + bias, 0.f);
        float pu = h * wla, pw = h * wlb;
        #pragma unroll
        for (int off = 32; off > 0; off >>= 1) {
            pu += __shfl_down(pu, off);
            pw += __shfl_down(pw, off);
        }
        if (lane == 0) { Up[wave][i] = pu; Wp[wave][i] = pw; }
        S += add - sub;
    }
    __syncthreads();
    if (t < 32) {
        u[v0 + t] = Up[0][t] + Up[1][t] + Up[2][t] + Up[3][t];
        w[v0 + t] = Wp[0][t] + Wp[1][t] + Wp[2][t] + Wp[3][t];
    }
}

// ---------------- P[v] = u[v] + 16*w[v] + sum_{o=1..8}(u[v+o]+u[v-o]) ----------
__global__ __launch_bounds__(256) void compP(const float* __restrict__ u,
                                             const float* __restrict__ w,
                                             float* __restrict__ P)
{
    const int v = blockIdx.x * 256 + threadIdx.x;
    if (v >= NN) return;
    float s = u[v] + 16.0f * w[v];
    #pragma unroll
    for (int o = 1; o <= 8; ++o) {
        int vp = v + o;  if (vp >= NN) vp -= NN;
        int vm = v - o;  if (vm < 0)   vm += NN;
        s += u[vp] + u[vm];
    }
    P[v] = s;
}

// ---------------- final per-edge output ----------------
__global__ __launch_bounds__(256) void out_kernel(const float* __restrict__ P,
                                                  const float* __restrict__ w,
                                                  const float* __restrict__ blp,
                                                  float* __restrict__ out)
{
    const int c = blockIdx.x * 256 + threadIdx.x;
    if (c >= NEDGE) return;
    int v, tt;
    if (c < NK) {
        v = c >> 3;
        tt = v + 1 + (c & 7);
        if (tt >= NN) tt -= NN;
    } else {
        const int e = c - NK;
        tt = e >> 3;
        v = tt + 1 + (e & 7);
        if (v >= NN) v -= NN;
    }
    const float val = (P[v] + w[tt]) * (1.0f / 17.0f) + blp[0];
    out[c] = sigmoidf_(val);
}

// ---------------- launch ----------------
extern "C" void kernel_launch(void* const* d_in, const int* in_sizes, int n_in,
                              void* d_out, int out_size, void* d_ws, size_t ws_size,
                              hipStream_t stream)
{
    const float* x      = (const float*)d_in[0];
    const float* W1     = (const float*)d_in[1];
    const float* b1     = (const float*)d_in[2];
    const float* gamma1 = (const float*)d_in[3];
    const float* beta1  = (const float*)d_in[4];
    const float* W2     = (const float*)d_in[5];
    const float* b2     = (const float*)d_in[6];
    const float* Wl     = (const float*)d_in[7];
    const float* bl     = (const float*)d_in[8];
    float* out = (float*)d_out;

    // workspace layout (float-sized units for convenience)
    float* A    = (float*)d_ws;                       // [NN,256] f32      20.48 MB
    float* H    = A + (size_t)NN * 256;               // [NN,256] f32      20.48 MB (H1/H2)
    float* part = H + (size_t)NN * 256;               // [625,512] f32      1.28 MB
    float* ss   = part + 625 * 512;                   // [512]
    float* u    = ss + 512;                           // [NN]
    float* wv   = u + NN;                             // [NN]
    float* P    = wv + NN;                            // [NN]
    ushort* xb  = (ushort*)(P + NN);                  // [NN,128] bf16      5.12 MB
    ushort* W1t = xb + (size_t)NN * 128;              // [256,128] bf16
    ushort* W2t = W1t + 256 * 128;                    // [256,256] bf16
    ushort* h1b = W2t + 256 * 256;                    // [NN,256] bf16     10.24 MB

    // 1) prep: casts + weight transposes
    prep_kernel<<<2596, 256, 0, stream>>>(x, W1, W2, xb, W1t, W2t);
    // 2) H1 = x @ W1   (bf16 MFMA)
    dim3 g1(313, 4);
    gemm_bf16<128><<<g1, 256, 0, stream>>>(xb, W1t, H);
    // 3) agg1 + b1 -> A, fused BN partials
    agg1_bn<<<625, 256, 0, stream>>>(H, b1, A, part);
    // 4) BN finalize -> scale/shift
    bn_finalize<<<1, 512, 0, stream>>>(part, gamma1, beta1, ss);
    // 5) BN apply + relu + cast -> h1b
    bn_relu_cast<<<5000, 256, 0, stream>>>(A, ss, h1b);
    // 6) H2 = h1 @ W2  (bf16 MFMA)
    gemm_bf16<256><<<g1, 256, 0, stream>>>(h1b, W2t, H);
    // 7) agg2 + b2 + relu + dots -> u, w
    agg2_dots<<<625, 256, 0, stream>>>(H, b2, Wl, u, wv);
    // 8) P
    compP<<<(NN + 255) / 256, 256, 0, stream>>>(u, wv, P);
    // 9) edge outputs
    out_kernel<<<(NEDGE + 255) / 256, 256, 0, stream>>>(P, wv, bl, out);
}

// Round 3
// 68.865 us; speedup vs baseline: 2.0325x; 1.6927x over previous
//
#include <hip/hip_runtime.h>
#include <hip/hip_bf16.h>
#include <math.h>

#define NN    20000
#define NK    160000          // NN*8
#define NEDGE 320000
#define HID   256
#define INFEAT 128
#define EPSF  1e-5f

typedef __bf16 bf16x8 __attribute__((ext_vector_type(8)));
typedef float  f32x4  __attribute__((ext_vector_type(4)));

__device__ __forceinline__ float sigmoidf_(float x) { return 1.0f / (1.0f + expf(-x)); }

__device__ __forceinline__ ushort f2bf(float f) {
    __hip_bfloat16 h = __float2bfloat16(f);
    return __builtin_bit_cast(ushort, h);
}
__device__ __forceinline__ float bf2f(ushort u) {
    return __builtin_bit_cast(float, ((unsigned int)u) << 16);
}

__device__ __forceinline__ int wrapN(int v) {
    return (v < 0) ? v + NN : ((v >= NN) ? v - NN : v);
}

#define LDSP(p) ((__attribute__((address_space(3))) unsigned int*)(p))
#define GBLP(p) ((const __attribute__((address_space(1))) unsigned int*)(p))
#define GLD16(g, l) __builtin_amdgcn_global_load_lds(GBLP(g), LDSP(l), 16, 0, 0)

// ---------------- prep: cast x -> bf16; build W1^T, W2^T in bf16 ----------------
__global__ __launch_bounds__(256) void prep_kernel(const float* __restrict__ x,
                                                   const float* __restrict__ W1,
                                                   const float* __restrict__ W2,
                                                   ushort* __restrict__ xb,
                                                   ushort* __restrict__ W1t,
                                                   ushort* __restrict__ W2t)
{
    const int b = blockIdx.x, t = threadIdx.x;
    if (b < 2500) {
        const int idx = b * 1024 + t * 4;
        const float4 v = *reinterpret_cast<const float4*>(x + idx);
        ushort4 o; o.x = f2bf(v.x); o.y = f2bf(v.y); o.z = f2bf(v.z); o.w = f2bf(v.w);
        *reinterpret_cast<ushort4*>(xb + idx) = o;
    } else if (b < 2532) {
        const int e = (b - 2500) * 1024 + t * 4;   // 32768 elements
        ushort4 o;
        #pragma unroll
        for (int j = 0; j < 4; ++j) {
            const int ee = e + j;
            const int n = ee >> 7, k = ee & 127;   // W1t[n][k] = W1[k][n]
            ((ushort*)&o)[j] = f2bf(W1[k * 256 + n]);
        }
        *reinterpret_cast<ushort4*>(W1t + e) = o;
    } else {
        const int e = (b - 2532) * 1024 + t * 4;   // 65536 elements
        ushort4 o;
        #pragma unroll
        for (int j = 0; j < 4; ++j) {
            const int ee = e + j;
            const int n = ee >> 8, k = ee & 255;   // W2t[n][k] = W2[k][n]
            ((ushort*)&o)[j] = f2bf(W2[k * 256 + n]);
        }
        *reinterpret_cast<ushort4*>(W2t + e) = o;
    }
}

// ---------------- MFMA bf16 GEMM: C[M,256] = A[M,K] @ B (Bt[256][K]), bf16 out ----
template<int K>
__global__ __launch_bounds__(256) void gemm_bf16(const ushort* __restrict__ Ab,
                                                 const ushort* __restrict__ Bt,
                                                 ushort* __restrict__ C)
{
    __shared__ alignas(16) char As[8192];
    __shared__ alignas(16) char Bs[8192];

    const int bm = blockIdx.x * 64;
    const int bn = blockIdx.y * 64;
    const int t = threadIdx.x;
    const int wave = t >> 6, lane = t & 63;
    const int wr = (wave >> 1) * 32;
    const int wc = (wave & 1) * 32;

    f32x4 acc[2][2] = {};

    for (int kt = 0; kt < K / 64; ++kt) {
        const int k0 = kt * 64;
        #pragma unroll
        for (int j = 0; j < 2; ++j) {
            const int c   = (wave + 4 * j) * 64 + lane;
            const int row = c >> 3;
            const int pk  = (c & 7) << 4;
            const int lk  = pk ^ ((row & 7) << 4);
            int rg = bm + row; if (rg >= NN) rg = NN - 1;
            GLD16(Ab + (size_t)rg * K + k0 + (lk >> 1), As + (wave + 4 * j) * 1024);
            GLD16(Bt + (size_t)(bn + row) * K + k0 + (lk >> 1), Bs + (wave + 4 * j) * 1024);
        }
        __syncthreads();

        #pragma unroll
        for (int kk = 0; kk < 2; ++kk) {
            const int klog = kk * 64 + ((lane >> 4) << 4);
            bf16x8 af[2], bfv[2];
            #pragma unroll
            for (int mi = 0; mi < 2; ++mi) {
                const int row = wr + mi * 16 + (lane & 15);
                af[mi] = *reinterpret_cast<const bf16x8*>(As + row * 128 + (klog ^ ((row & 7) << 4)));
            }
            #pragma unroll
            for (int ni = 0; ni < 2; ++ni) {
                const int row = wc + ni * 16 + (lane & 15);
                bfv[ni] = *reinterpret_cast<const bf16x8*>(Bs + row * 128 + (klog ^ ((row & 7) << 4)));
            }
            #pragma unroll
            for (int mi = 0; mi < 2; ++mi)
                #pragma unroll
                for (int ni = 0; ni < 2; ++ni)
                    acc[mi][ni] = __builtin_amdgcn_mfma_f32_16x16x32_bf16(af[mi], bfv[ni], acc[mi][ni], 0, 0, 0);
        }
        __syncthreads();
    }

    #pragma unroll
    for (int mi = 0; mi < 2; ++mi)
        #pragma unroll
        for (int ni = 0; ni < 2; ++ni)
            #pragma unroll
            for (int r = 0; r < 4; ++r) {
                const int row = bm + wr + mi * 16 + ((lane >> 4) << 2) + r;
                if (row < NN)
                    C[(size_t)row * 256 + bn + wc + ni * 16 + (lane & 15)] = f2bf(acc[mi][ni][r]);
            }
}

// ---------------- agg1 (rolling 17-tap) + bias, fused BN partial stats ----------
__global__ __launch_bounds__(256) void agg1_bn(const ushort* __restrict__ H1,
                                               const float* __restrict__ b1,
                                               ushort* __restrict__ A,
                                               float* __restrict__ part)
{
    const int b = blockIdx.x, f = threadIdx.x;
    const int v0 = b * 32;
    const float bias = b1[f];
    float S = 0.f;
    #pragma unroll
    for (int o = -8; o <= 8; ++o)
        S += bf2f(H1[(size_t)wrapN(v0 + o) * 256 + f]);
    float s = 0.f, s2 = 0.f;
    const float inv17 = 1.0f / 17.0f;
    for (int i = 0; i < 32; ++i) {
        const int v = v0 + i;
        const float add = bf2f(H1[(size_t)wrapN(v + 9) * 256 + f]);
        const float sub = bf2f(H1[(size_t)wrapN(v - 8) * 256 + f]);
        const float val = S * inv17 + bias;
        A[(size_t)v * 256 + f] = f2bf(val);
        s += val; s2 += val * val;
        S += add - sub;
    }
    part[(size_t)b * 512 + f]       = s;
    part[(size_t)b * 512 + 256 + f] = s2;
}

// ---------------- BN reduce: 625 partials -> 25 ----------------
__global__ __launch_bounds__(512) void bn_reduce(const float* __restrict__ part,
                                                 float* __restrict__ part2)
{
    const int b = blockIdx.x, t = threadIdx.x;
    float s = 0.f;
    #pragma unroll 5
    for (int r = b * 25; r < b * 25 + 25; ++r)
        s += part[(size_t)r * 512 + t];
    part2[(size_t)b * 512 + t] = s;
}

__global__ __launch_bounds__(512) void bn_finalize(const float* __restrict__ part2,
                                                   const float* __restrict__ gamma,
                                                   const float* __restrict__ beta,
                                                   float* __restrict__ ss)
{
    const int t = threadIdx.x;
    __shared__ float red[512];
    float s = 0.f;
    #pragma unroll 5
    for (int b = 0; b < 25; ++b)
        s += part2[(size_t)b * 512 + t];
    red[t] = s;
    __syncthreads();
    if (t < 256) {
        const float invn = 1.0f / (float)NN;
        const float mu   = red[t] * invn;
        const float var  = red[t + 256] * invn - mu * mu;
        const float sc   = gamma[t] * rsqrtf(var + EPSF);
        ss[t]       = sc;
        ss[256 + t] = beta[t] - mu * sc;
    }
}

// ---------------- BN apply + relu (bf16 in/out) ----------------
__global__ __launch_bounds__(256) void bn_relu_cast(const ushort* __restrict__ A,
                                                    const float* __restrict__ ss,
                                                    ushort* __restrict__ h1b)
{
    const int idx = blockIdx.x * 256 + threadIdx.x;   // 8 elems per thread
    const int f = (idx & 31) << 3;
    ushort4 lo = *reinterpret_cast<const ushort4*>(A + (size_t)idx * 8);
    ushort4 hi = *reinterpret_cast<const ushort4*>(A + (size_t)idx * 8 + 4);
    ushort4 olo, ohi;
    #pragma unroll
    for (int j = 0; j < 4; ++j) {
        const float v0 = bf2f(((const ushort*)&lo)[j]);
        const float v1 = bf2f(((const ushort*)&hi)[j]);
        ((ushort*)&olo)[j] = f2bf(fmaxf(v0 * ss[f + j]     + ss[256 + f + j],     0.f));
        ((ushort*)&ohi)[j] = f2bf(fmaxf(v1 * ss[f + 4 + j] + ss[256 + f + 4 + j], 0.f));
    }
    *reinterpret_cast<ushort4*>(h1b + (size_t)idx * 8)     = olo;
    *reinterpret_cast<ushort4*>(h1b + (size_t)idx * 8 + 4) = ohi;
}

// ---------------- agg2 (rolling) + bias + relu + dot with Wl -> u, w ----------
__global__ __launch_bounds__(256) void agg2_dots(const ushort* __restrict__ H2,
                                                 const float* __restrict__ b2,
                                                 const float* __restrict__ Wl,
                                                 float* __restrict__ u,
                                                 float* __restrict__ w)
{
    const int b = blockIdx.x, t = threadIdx.x;
    const int wave = t >> 6, lane = t & 63;
    const int v0 = b * 32;
    const float wla = Wl[t], wlb = Wl[256 + t], bias = b2[t];
    __shared__ float Up[4][32], Wp[4][32];

    float S = 0.f;
    #pragma unroll
    for (int o = -8; o <= 8; ++o)
        S += bf2f(H2[(size_t)wrapN(v0 + o) * 256 + t]);

    const float inv17 = 1.0f / 17.0f;
    for (int i = 0; i < 32; ++i) {
        const int v = v0 + i;
        const float add = bf2f(H2[(size_t)wrapN(v + 9) * 256 + t]);
        const float sub = bf2f(H2[(size_t)wrapN(v - 8) * 256 + t]);
        const float h = fmaxf(S * inv17 + bias, 0.f);
        float pu = h * wla, pw = h * wlb;
        #pragma unroll
        for (int off = 32; off > 0; off >>= 1) {
            pu += __shfl_down(pu, off);
            pw += __shfl_down(pw, off);
        }
        if (lane == 0) { Up[wave][i] = pu; Wp[wave][i] = pw; }
        S += add - sub;
    }
    __syncthreads();
    if (t < 32) {
        u[v0 + t] = Up[0][t] + Up[1][t] + Up[2][t] + Up[3][t];
        w[v0 + t] = Wp[0][t] + Wp[1][t] + Wp[2][t] + Wp[3][t];
    }
}

// ---------------- P[v] = u[v] + 16*w[v] + sum_{o=1..8}(u[v+o]+u[v-o]) ----------
__global__ __launch_bounds__(256) void compP(const float* __restrict__ u,
                                             const float* __restrict__ w,
                                             float* __restrict__ P)
{
    const int v = blockIdx.x * 256 + threadIdx.x;
    if (v >= NN) return;
    float s = u[v] + 16.0f * w[v];
    #pragma unroll
    for (int o = 1; o <= 8; ++o) {
        int vp = v + o;  if (vp >= NN) vp -= NN;
        int vm = v - o;  if (vm < 0)   vm += NN;
        s += u[vp] + u[vm];
    }
    P[v] = s;
}

// ---------------- final per-edge output ----------------
__global__ __launch_bounds__(256) void out_kernel(const float* __restrict__ P,
                                                  const float* __restrict__ w,
                                                  const float* __restrict__ blp,
                                                  float* __restrict__ out)
{
    const int c = blockIdx.x * 256 + threadIdx.x;
    if (c >= NEDGE) return;
    int v, tt;
    if (c < NK) {
        v = c >> 3;
        tt = v + 1 + (c & 7);
        if (tt >= NN) tt -= NN;
    } else {
        const int e = c - NK;
        tt = e >> 3;
        v = tt + 1 + (e & 7);
        if (v >= NN) v -= NN;
    }
    const float val = (P[v] + w[tt]) * (1.0f / 17.0f) + blp[0];
    out[c] = sigmoidf_(val);
}

// ---------------- launch ----------------
extern "C" void kernel_launch(void* const* d_in, const int* in_sizes, int n_in,
                              void* d_out, int out_size, void* d_ws, size_t ws_size,
                              hipStream_t stream)
{
    const float* x      = (const float*)d_in[0];
    const float* W1     = (const float*)d_in[1];
    const float* b1     = (const float*)d_in[2];
    const float* gamma1 = (const float*)d_in[3];
    const float* beta1  = (const float*)d_in[4];
    const float* W2     = (const float*)d_in[5];
    const float* b2     = (const float*)d_in[6];
    const float* Wl     = (const float*)d_in[7];
    const float* bl     = (const float*)d_in[8];
    float* out = (float*)d_out;

    // f32 scratch first, then bf16 arrays (all 16B-aligned)
    float* part  = (float*)d_ws;                     // [625,512]
    float* part2 = part + 625 * 512;                 // [25,512]
    float* ss    = part2 + 25 * 512;                 // [512]
    float* u     = ss + 512;                         // [NN]
    float* wv    = u + NN;                           // [NN]
    float* P     = wv + NN;                          // [NN]
    ushort* A    = (ushort*)(P + NN);                // [NN,256] bf16
    ushort* H    = A + (size_t)NN * 256;             // [NN,256] bf16 (H1/H2)
    ushort* xb   = H + (size_t)NN * 256;             // [NN,128] bf16
    ushort* W1t  = xb + (size_t)NN * 128;            // [256,128]
    ushort* W2t  = W1t + 256 * 128;                  // [256,256]
    ushort* h1b  = W2t + 256 * 256;                  // [NN,256] bf16

    // 1) prep: casts + weight transposes
    prep_kernel<<<2596, 256, 0, stream>>>(x, W1, W2, xb, W1t, W2t);
    // 2) H1 = x @ W1   (bf16 MFMA)
    dim3 g1(313, 4);
    gemm_bf16<128><<<g1, 256, 0, stream>>>(xb, W1t, H);
    // 3) agg1 + b1 -> A (bf16), fused BN partials
    agg1_bn<<<625, 256, 0, stream>>>(H, b1, A, part);
    // 4) BN reduce (parallel) + finalize
    bn_reduce<<<25, 512, 0, stream>>>(part, part2);
    bn_finalize<<<1, 512, 0, stream>>>(part2, gamma1, beta1, ss);
    // 5) BN apply + relu -> h1b
    bn_relu_cast<<<2500, 256, 0, stream>>>(A, ss, h1b);
    // 6) H2 = h1 @ W2  (bf16 MFMA)
    gemm_bf16<256><<<g1, 256, 0, stream>>>(h1b, W2t, H);
    // 7) agg2 + b2 + relu + dots -> u, w
    agg2_dots<<<625, 256, 0, stream>>>(H, b2, Wl, u, wv);
    // 8) P
    compP<<<(NN + 255) / 256, 256, 0, stream>>>(u, wv, P);
    // 9) edge outputs
    out_kernel<<<(NEDGE + 255) / 256, 256, 0, stream>>>(P, wv, bl, out);
}